// Round 11
// baseline (370.358 us; speedup 1.0000x reference)
//
#include <hip/hip_runtime.h>
#include <hip/hip_bf16.h>
#include <cstdint>
#include <cstddef>

#define DEV __device__ __forceinline__

typedef __attribute__((ext_vector_type(8))) __bf16 bfrag8;           // MFMA A/B operand
typedef __attribute__((ext_vector_type(4))) float f32x4;             // MFMA C/D (16x16)
typedef __attribute__((ext_vector_type(8))) unsigned short u16x8;
typedef __attribute__((ext_vector_type(4))) unsigned short u16x4;

static constexpr int S = 2048, D = 1024;
static constexpr size_t XN = (size_t)4 * 2048 * 1024;   // 8388608 (B*S*D)
static constexpr size_t WN = (size_t)1024 * 1024;       // 1048576 (D*D)

DEV unsigned short bfu(float f) {
  return __builtin_bit_cast(unsigned short, (__bf16)f);
}

#define GLOAD16(g, l)                                                          \
  __builtin_amdgcn_global_load_lds(                                            \
      (const __attribute__((address_space(1))) void*)(g),                      \
      (__attribute__((address_space(3))) void*)(l), 16, 0, 0)

#define VMW4 asm volatile("s_waitcnt vmcnt(4)" ::: "memory")
#define VMW0 asm volatile("s_waitcnt vmcnt(0)" ::: "memory")
#define BAR()                                                                  \
  do {                                                                         \
    asm volatile("" ::: "memory");                                             \
    __builtin_amdgcn_s_barrier();                                              \
    asm volatile("" ::: "memory");                                             \
  } while (0)

// ---------------------------------------------------------------------------
// f32 -> bf16 conversion of x, Wq, Wk, Wv, Wo into one contiguous ws region
// ---------------------------------------------------------------------------
__global__ __launch_bounds__(256) void convert_kernel(
    const float* __restrict__ x, const float* __restrict__ wq,
    const float* __restrict__ wk, const float* __restrict__ wv,
    const float* __restrict__ wo, unsigned short* __restrict__ dst) {
  size_t i = ((size_t)blockIdx.x * 256 + threadIdx.x) * 8;
  const float* src;
  size_t off;
  if (i < XN) { src = x; off = i; }
  else if (i < XN + WN)     { src = wq; off = i - XN; }
  else if (i < XN + 2 * WN) { src = wk; off = i - (XN + WN); }
  else if (i < XN + 3 * WN) { src = wv; off = i - (XN + 2 * WN); }
  else                      { src = wo; off = i - (XN + 3 * WN); }
  const float4* p = (const float4*)(src + off);
  float4 a = p[0], b = p[1];
  u16x8 o;
  o[0] = bfu(a.x); o[1] = bfu(a.y); o[2] = bfu(a.z); o[3] = bfu(a.w);
  o[4] = bfu(b.x); o[5] = bfu(b.y); o[6] = bfu(b.z); o[7] = bfu(b.w);
  *(u16x8*)(dst + i) = o;
}

// ---------------------------------------------------------------------------
// Shared GEMM mainloop: C[128x128] = A[128xK] * B[128xK]^T  (NT, bf16, K=1024)
// ---------------------------------------------------------------------------
DEV void gemm_mainloop(const unsigned short* __restrict__ Ag,
                       const unsigned short* __restrict__ Bg,
                       unsigned short* ldsA, unsigned short* ldsB,
                       f32x4 (&acc)[4][4], int tid) {
  const int lane = tid & 63;
  const int wr = (tid >> 7) & 1;   // wave row (0..1)
  const int wc = (tid >> 6) & 1;   // wave col (0..1)
  for (int kt = 0; kt < 32; ++kt) {
#pragma unroll
    for (int i = 0; i < 2; ++i) {
      const int c = tid + i * 256;          // chunk id, 16B each; 512 chunks/tile
      const int row = c >> 2, ks = c & 3;   // 64B rows, 4 chunks/row
      const int ldsoff = ((tid & ~63) + i * 256) * 16;  // wave-uniform base
      GLOAD16(Ag + (size_t)row * 1024 + kt * 32 + ks * 8, (char*)ldsA + ldsoff);
      GLOAD16(Bg + (size_t)row * 1024 + kt * 32 + ks * 8, (char*)ldsB + ldsoff);
    }
    asm volatile("s_waitcnt vmcnt(0)" ::: "memory");
    __syncthreads();
    bfrag8 av[4], bv[4];
#pragma unroll
    for (int m = 0; m < 4; ++m)
      av[m] = *(const bfrag8*)(ldsA + (wr * 64 + m * 16 + (lane & 15)) * 32 +
                               (lane >> 4) * 8);
#pragma unroll
    for (int n = 0; n < 4; ++n)
      bv[n] = *(const bfrag8*)(ldsB + (wc * 64 + n * 16 + (lane & 15)) * 32 +
                               (lane >> 4) * 8);
#pragma unroll
    for (int m = 0; m < 4; ++m)
#pragma unroll
      for (int n = 0; n < 4; ++n)
        acc[m][n] =
            __builtin_amdgcn_mfma_f32_16x16x32_bf16(av[m], bv[n], acc[m][n], 0, 0, 0);
    __syncthreads();
  }
}

// ---------------------------------------------------------------------------
// QKV projection.  z=0 -> Q (bf16 [B,S,D]); z=1 -> K (bf16 [B,S,D]);
// z=2 -> V transposed per head (bf16 [B,H,HD,S]).
// ---------------------------------------------------------------------------
__global__ __launch_bounds__(256, 2) void gemm_qkv(
    const unsigned short* __restrict__ xbf, const unsigned short* __restrict__ wq,
    const unsigned short* __restrict__ wk, const unsigned short* __restrict__ wv,
    unsigned short* __restrict__ Qb, unsigned short* __restrict__ Kb,
    unsigned short* __restrict__ Vt) {
  __shared__ __align__(16) unsigned short ldsA[128 * 32];
  __shared__ __align__(16) unsigned short ldsB[128 * 32];
  const int tid = threadIdx.x;
  const int z = blockIdx.z;
  const unsigned short* W = (z == 0) ? wq : ((z == 1) ? wk : wv);
  const int m0 = blockIdx.y * 128, n0 = blockIdx.x * 128;

  f32x4 acc[4][4];
#pragma unroll
  for (int m = 0; m < 4; ++m)
#pragma unroll
    for (int n = 0; n < 4; ++n) acc[m][n] = (f32x4){0.f, 0.f, 0.f, 0.f};

  gemm_mainloop(xbf + (size_t)m0 * 1024, W + (size_t)n0 * 1024, ldsA, ldsB, acc, tid);

  const int lane = tid & 63;
  const int wr = (tid >> 7) & 1, wc = (tid >> 6) & 1;
  const int hi = lane >> 4, lo = lane & 15;
  if (z < 2) {
    unsigned short* dst = (z == 0) ? Qb : Kb;
#pragma unroll
    for (int m = 0; m < 4; ++m)
#pragma unroll
      for (int n = 0; n < 4; ++n)
#pragma unroll
        for (int r = 0; r < 4; ++r) {
          int row = m0 + wr * 64 + m * 16 + hi * 4 + r;
          int col = n0 + wc * 64 + n * 16 + lo;
          dst[(size_t)row * 1024 + col] = bfu(acc[m][n][r]);
        }
  } else {
    // V^T: [B,H,64,S]; lane's 4 acc values are 4 consecutive s -> 8B packed store
#pragma unroll
    for (int m = 0; m < 4; ++m)
#pragma unroll
      for (int n = 0; n < 4; ++n) {
        int col = n0 + wc * 64 + n * 16 + lo;
        int hh = col >> 6, hd = col & 63;
        int row0 = m0 + wr * 64 + m * 16 + hi * 4;
        int b_ = row0 >> 11, s_ = row0 & 2047;
        u16x4 pk;
#pragma unroll
        for (int r = 0; r < 4; ++r) pk[r] = bfu(acc[m][n][r]);
        *(u16x4*)(Vt + ((size_t)((b_ * 16 + hh) * 64 + hd)) * 2048 + s_) = pk;
      }
  }
}

// ---------------------------------------------------------------------------
// Output projection: out(f32) = O(bf16) * Wo^T
// ---------------------------------------------------------------------------
__global__ __launch_bounds__(256, 2) void gemm_out(
    const unsigned short* __restrict__ Ob, const unsigned short* __restrict__ wo,
    float* __restrict__ out) {
  __shared__ __align__(16) unsigned short ldsA[128 * 32];
  __shared__ __align__(16) unsigned short ldsB[128 * 32];
  const int tid = threadIdx.x;
  const int m0 = blockIdx.y * 128, n0 = blockIdx.x * 128;
  f32x4 acc[4][4];
#pragma unroll
  for (int m = 0; m < 4; ++m)
#pragma unroll
    for (int n = 0; n < 4; ++n) acc[m][n] = (f32x4){0.f, 0.f, 0.f, 0.f};
  gemm_mainloop(Ob + (size_t)m0 * 1024, wo + (size_t)n0 * 1024, ldsA, ldsB, acc, tid);
  const int lane = tid & 63;
  const int wr = (tid >> 7) & 1, wc = (tid >> 6) & 1;
  const int hi = lane >> 4, lo = lane & 15;
#pragma unroll
  for (int m = 0; m < 4; ++m)
#pragma unroll
    for (int n = 0; n < 4; ++n)
#pragma unroll
      for (int r = 0; r < 4; ++r) {
        int row = m0 + wr * 64 + m * 16 + hi * 4 + r;
        int col = n0 + wc * 64 + n * 16 + lo;
        out[(size_t)row * 1024 + col] = acc[m][n][r];
      }
}

// ---------------------------------------------------------------------------
// Flash attention, R10: R9 + (a) kv-permuted K-fragment loads so the PV
// B-operand is built FULLY IN-LANE (no ds_bpermute exchange at all), and
// (b) __launch_bounds__(256,4) — R9's 84-VGPR body fits the 128-reg budget,
// doubling occupancy to 4 blocks/CU (grid 1024 = exactly 4/CU).
//   τ: kf A-row lo of block n holds kv = (n&1)*32+(lo>>2)*8+(lo&3)*2+(n>>1)
//   => after QK^T lane holds kv = (n&1)*32 + hi*8 + r*2 + (n>>1), which is
//   exactly the PV B-claim set {kk*32+hi*8+j}: pb[kk][j]=sc[2*(j&1)+kk][j>>1].
//   Softmax is kv-symmetric so the relabeling is benign.
// ---------------------------------------------------------------------------
__global__ __launch_bounds__(256, 4) void attn_kernel(
    const unsigned short* __restrict__ Qb, const unsigned short* __restrict__ Kb,
    const unsigned short* __restrict__ Vt, unsigned short* __restrict__ Ob) {
  __shared__ __align__(16) unsigned short K0[64 * 64];
  __shared__ __align__(16) unsigned short K1[64 * 64];
  __shared__ __align__(16) unsigned short V0[64 * 64];
  __shared__ __align__(16) unsigned short V1[64 * 64];

  const int tid = threadIdx.x, lane = tid & 63, wave = tid >> 6;
  const int hi = lane >> 4, lo = lane & 15;

  // XCD-aware bijective swizzle: 1024 blocks = 8 XCDs x 128 work items.
  const int lin = blockIdx.x;
  const int wid = (lin & 7) * 128 + (lin >> 3);
  const int bh = wid >> 4, qt = wid & 15;
  const int b = bh >> 4, h = bh & 15;

  const unsigned short* Qg = Qb + (size_t)(b * S + qt * 128) * D + h * 64;
  const unsigned short* Kg = Kb + (size_t)b * S * D + h * 64;
  const unsigned short* Vg = Vt + (size_t)bh * 64 * S;

  // Q fragments (B-operand): lane holds Q[q=wave*32+m*16+lo][d=kk*32+hi*8..+7]
  bfrag8 qf[2][2];
#pragma unroll
  for (int m = 0; m < 2; ++m)
#pragma unroll
    for (int kk = 0; kk < 2; ++kk)
      qf[m][kk] =
          *(const bfrag8*)(Qg + (size_t)(wave * 32 + m * 16 + lo) * D + kk * 32 + hi * 8);

  // O^T accumulators: oT[n][m] reg r -> d = n*16+hi*4+r, q = m*16+lo
  f32x4 oT[4][2];
  float mrow[2], lrow[2];
#pragma unroll
  for (int n = 0; n < 4; ++n)
#pragma unroll
    for (int m = 0; m < 2; ++m) oT[n][m] = (f32x4){0.f, 0.f, 0.f, 0.f};
  mrow[0] = mrow[1] = -__builtin_inff();
  lrow[0] = lrow[1] = 0.f;

  // stage one KV tile (16KB); XOR swizzle via pre-swizzled global source
  auto stage = [&](unsigned short* kl, unsigned short* vl, int kv0) {
#pragma unroll
    for (int i = 0; i < 2; ++i) {
      int c = tid + i * 256;                      // 512 chunks per 8KB tile
      int row = c >> 3, sl = (c & 7) ^ (row & 7); // pre-swizzled source slot
      int ldsoff = ((tid & ~63) + i * 256) * 16;
      GLOAD16(Kg + (size_t)(kv0 + row) * D + sl * 8, (char*)kl + ldsoff);
      GLOAD16(Vg + (size_t)row * S + kv0 + sl * 8, (char*)vl + ldsoff);
    }
  };

  auto compute = [&](const unsigned short* Kc, const unsigned short* Vc) {
    const float c1 = 0.125f * 1.4426950408889634f;  // scale * log2(e)
    // K fragments (A-operand), kv-permuted rows (τ): see header comment.
    bfrag8 kf[4][2];
#pragma unroll
    for (int n = 0; n < 4; ++n) {
      const int row = (n & 1) * 32 + (lo >> 2) * 8 + (lo & 3) * 2 + (n >> 1);
#pragma unroll
      for (int kk = 0; kk < 2; ++kk)
        kf[n][kk] = *(const bfrag8*)(Kc + row * 64 + (((kk * 4 + hi) ^ (row & 7)) * 8));
    }
    // S^T: sc[n][m] reg r -> kv = (n&1)*32 + hi*8 + r*2 + (n>>1), q = m*16+lo
    f32x4 sc[4][2];
#pragma unroll
    for (int n = 0; n < 4; ++n)
#pragma unroll
      for (int m = 0; m < 2; ++m) {
        sc[n][m] = (f32x4){0.f, 0.f, 0.f, 0.f};
#pragma unroll
        for (int kk = 0; kk < 2; ++kk)
          sc[n][m] = __builtin_amdgcn_mfma_f32_16x16x32_bf16(kf[n][kk], qf[m][kk],
                                                             sc[n][m], 0, 0, 0);
      }
    // V^T fragments (A-operand for O^T): row d = n*16+lo, k-chunk kv = kk*32+hi*8
    bfrag8 vf[4][2];
#pragma unroll
    for (int n = 0; n < 4; ++n)
#pragma unroll
      for (int kk = 0; kk < 2; ++kk) {
        int row = n * 16 + lo;
        vf[n][kk] = *(const bfrag8*)(Vc + row * 64 + (((kk * 4 + hi) ^ (row & 7)) * 8));
      }

#pragma unroll
    for (int m = 0; m < 2; ++m) {
      // softmax for q = m*16+lo: 16 in-lane kv values + reduce across hi
      float mx = sc[0][m][0];
#pragma unroll
      for (int n = 0; n < 4; ++n)
#pragma unroll
        for (int r = 0; r < 4; ++r)
          if (!(n == 0 && r == 0)) mx = fmaxf(mx, sc[n][m][r]);
      mx = fmaxf(mx, __shfl_xor(mx, 16));
      mx = fmaxf(mx, __shfl_xor(mx, 32));
      float Mnew = fmaxf(mrow[m], mx * c1);
      float alpha = __builtin_amdgcn_exp2f(mrow[m] - Mnew);
      float ps = 0.f;
#pragma unroll
      for (int n = 0; n < 4; ++n)
#pragma unroll
        for (int r = 0; r < 4; ++r) {
          float p = __builtin_amdgcn_exp2f(sc[n][m][r] * c1 - Mnew);
          sc[n][m][r] = p;
          ps += p;
        }
      ps += __shfl_xor(ps, 16);
      ps += __shfl_xor(ps, 32);
      lrow[m] = lrow[m] * alpha + ps;
      mrow[m] = Mnew;
#pragma unroll
      for (int n = 0; n < 4; ++n)
#pragma unroll
        for (int r = 0; r < 4; ++r) oT[n][m][r] *= alpha;

      // PV B-operand, fully in-lane: pb[kk] elem j = P[kv=kk*32+hi*8+j][q]
#pragma unroll
      for (int kk = 0; kk < 2; ++kk) {
        u16x8 pw;
#pragma unroll
        for (int j = 0; j < 8; ++j) pw[j] = bfu(sc[2 * (j & 1) + kk][m][j >> 1]);
        bfrag8 pb = __builtin_bit_cast(bfrag8, pw);
#pragma unroll
        for (int n = 0; n < 4; ++n)
          oT[n][m] = __builtin_amdgcn_mfma_f32_16x16x32_bf16(vf[n][kk], pb,
                                                             oT[n][m], 0, 0, 0);
      }
    }
  };

  stage(K0, V0, 0);
  for (int t = 0; t < 32; t += 2) {
    stage(K1, V1, (t + 1) * 64);    // prefetch odd tile (stays in flight)
    VMW4;                           // drain even tile only
    BAR();
    compute(K0, V0);
    BAR();                          // all reads of K0/V0 done
    if (t + 2 < 32) {
      stage(K0, V0, (t + 2) * 64);  // prefetch next even tile
      VMW4;                         // drain odd tile only
    } else {
      VMW0;
    }
    BAR();
    compute(K1, V1);
    BAR();                          // all reads of K1/V1 done
  }

  // epilogue: O^T[d][q] -> O rows q = wave*32+m*16+lo, d = n*16+hi*4+r
#pragma unroll
  for (int m = 0; m < 2; ++m) {
    float inv = 1.f / lrow[m];
    size_t qrow = (size_t)(b * S + qt * 128 + wave * 32 + m * 16 + lo) * D + h * 64;
#pragma unroll
    for (int n = 0; n < 4; ++n) {
      u16x4 p4;
#pragma unroll
      for (int r = 0; r < 4; ++r) p4[r] = bfu(oT[n][m][r] * inv);
      *(u16x4*)(Ob + qrow + n * 16 + hi * 4) = p4;
    }
  }
}

// ---------------------------------------------------------------------------
extern "C" void kernel_launch(void* const* d_in, const int* in_sizes, int n_in,
                              void* d_out, int out_size, void* d_ws, size_t ws_size,
                              hipStream_t stream) {
  const float* x = (const float*)d_in[0];
  const float* wq = (const float*)d_in[1];
  const float* wk = (const float*)d_in[2];
  const float* wv = (const float*)d_in[3];
  const float* wo = (const float*)d_in[4];
  float* out = (float*)d_out;

  unsigned short* base = (unsigned short*)d_ws;
  unsigned short* xbf = base;              // XN
  unsigned short* wqb = xbf + XN;          // WN
  unsigned short* wkb = wqb + WN;
  unsigned short* wvb = wkb + WN;
  unsigned short* wob = wvb + WN;
  unsigned short* Qb = wob + WN;           // XN
  unsigned short* Kb = Qb + XN;            // XN
  unsigned short* Vt = Kb + XN;            // XN  ([B,H,64,S])
  unsigned short* Ob = Vt + XN;            // XN

  convert_kernel<<<dim3(6144), dim3(256), 0, stream>>>(x, wq, wk, wv, wo, xbf);
  gemm_qkv<<<dim3(8, 64, 3), dim3(256), 0, stream>>>(xbf, wqb, wkb, wvb, Qb, Kb, Vt);
  attn_kernel<<<dim3(1024), dim3(256), 0, stream>>>(Qb, Kb, Vt, Ob);
  gemm_out<<<dim3(8, 64), dim3(256), 0, stream>>>(Ob, wob, out);
}

// Round 12
// 321.135 us; speedup vs baseline: 1.1533x; 1.1533x over previous
//
#include <hip/hip_runtime.h>
#include <hip/hip_bf16.h>
#include <cstdint>
#include <cstddef>

#define DEV __device__ __forceinline__

typedef __attribute__((ext_vector_type(8))) __bf16 bfrag8;           // MFMA A/B operand
typedef __attribute__((ext_vector_type(4))) float f32x4;             // MFMA C/D (16x16)
typedef __attribute__((ext_vector_type(8))) unsigned short u16x8;
typedef __attribute__((ext_vector_type(4))) unsigned short u16x4;

static constexpr int S = 2048, D = 1024;
static constexpr size_t XN = (size_t)4 * 2048 * 1024;   // 8388608 (B*S*D)
static constexpr size_t WN = (size_t)1024 * 1024;       // 1048576 (D*D)

DEV unsigned short bfu(float f) {
  return __builtin_bit_cast(unsigned short, (__bf16)f);
}

#define GLOAD16(g, l)                                                          \
  __builtin_amdgcn_global_load_lds(                                            \
      (const __attribute__((address_space(1))) void*)(g),                      \
      (__attribute__((address_space(3))) void*)(l), 16, 0, 0)

#define VMW4 asm volatile("s_waitcnt vmcnt(4)" ::: "memory")
#define VMW0 asm volatile("s_waitcnt vmcnt(0)" ::: "memory")
#define BAR()                                                                  \
  do {                                                                         \
    asm volatile("" ::: "memory");                                             \
    __builtin_amdgcn_s_barrier();                                              \
    asm volatile("" ::: "memory");                                             \
  } while (0)

// ---------------------------------------------------------------------------
// f32 -> bf16 conversion of x, Wq, Wk, Wv, Wo into one contiguous ws region
// ---------------------------------------------------------------------------
__global__ __launch_bounds__(256) void convert_kernel(
    const float* __restrict__ x, const float* __restrict__ wq,
    const float* __restrict__ wk, const float* __restrict__ wv,
    const float* __restrict__ wo, unsigned short* __restrict__ dst) {
  size_t i = ((size_t)blockIdx.x * 256 + threadIdx.x) * 8;
  const float* src;
  size_t off;
  if (i < XN) { src = x; off = i; }
  else if (i < XN + WN)     { src = wq; off = i - XN; }
  else if (i < XN + 2 * WN) { src = wk; off = i - (XN + WN); }
  else if (i < XN + 3 * WN) { src = wv; off = i - (XN + 2 * WN); }
  else                      { src = wo; off = i - (XN + 3 * WN); }
  const float4* p = (const float4*)(src + off);
  float4 a = p[0], b = p[1];
  u16x8 o;
  o[0] = bfu(a.x); o[1] = bfu(a.y); o[2] = bfu(a.z); o[3] = bfu(a.w);
  o[4] = bfu(b.x); o[5] = bfu(b.y); o[6] = bfu(b.z); o[7] = bfu(b.w);
  *(u16x8*)(dst + i) = o;
}

// ---------------------------------------------------------------------------
// Shared GEMM mainloop: C[128x128] = A[128xK] * B[128xK]^T  (NT, bf16, K=1024)
// ---------------------------------------------------------------------------
DEV void gemm_mainloop(const unsigned short* __restrict__ Ag,
                       const unsigned short* __restrict__ Bg,
                       unsigned short* ldsA, unsigned short* ldsB,
                       f32x4 (&acc)[4][4], int tid) {
  const int lane = tid & 63;
  const int wr = (tid >> 7) & 1;   // wave row (0..1)
  const int wc = (tid >> 6) & 1;   // wave col (0..1)
  for (int kt = 0; kt < 32; ++kt) {
#pragma unroll
    for (int i = 0; i < 2; ++i) {
      const int c = tid + i * 256;          // chunk id, 16B each; 512 chunks/tile
      const int row = c >> 2, ks = c & 3;   // 64B rows, 4 chunks/row
      const int ldsoff = ((tid & ~63) + i * 256) * 16;  // wave-uniform base
      GLOAD16(Ag + (size_t)row * 1024 + kt * 32 + ks * 8, (char*)ldsA + ldsoff);
      GLOAD16(Bg + (size_t)row * 1024 + kt * 32 + ks * 8, (char*)ldsB + ldsoff);
    }
    asm volatile("s_waitcnt vmcnt(0)" ::: "memory");
    __syncthreads();
    bfrag8 av[4], bv[4];
#pragma unroll
    for (int m = 0; m < 4; ++m)
      av[m] = *(const bfrag8*)(ldsA + (wr * 64 + m * 16 + (lane & 15)) * 32 +
                               (lane >> 4) * 8);
#pragma unroll
    for (int n = 0; n < 4; ++n)
      bv[n] = *(const bfrag8*)(ldsB + (wc * 64 + n * 16 + (lane & 15)) * 32 +
                               (lane >> 4) * 8);
#pragma unroll
    for (int m = 0; m < 4; ++m)
#pragma unroll
      for (int n = 0; n < 4; ++n)
        acc[m][n] =
            __builtin_amdgcn_mfma_f32_16x16x32_bf16(av[m], bv[n], acc[m][n], 0, 0, 0);
    __syncthreads();
  }
}

// ---------------------------------------------------------------------------
// QKV projection.  z=0 -> Q (bf16 [B,S,D]); z=1 -> K (bf16 [B,S,D]);
// z=2 -> V transposed per head (bf16 [B,H,HD,S]).
// ---------------------------------------------------------------------------
__global__ __launch_bounds__(256, 2) void gemm_qkv(
    const unsigned short* __restrict__ xbf, const unsigned short* __restrict__ wq,
    const unsigned short* __restrict__ wk, const unsigned short* __restrict__ wv,
    unsigned short* __restrict__ Qb, unsigned short* __restrict__ Kb,
    unsigned short* __restrict__ Vt) {
  __shared__ __align__(16) unsigned short ldsA[128 * 32];
  __shared__ __align__(16) unsigned short ldsB[128 * 32];
  const int tid = threadIdx.x;
  const int z = blockIdx.z;
  const unsigned short* W = (z == 0) ? wq : ((z == 1) ? wk : wv);
  const int m0 = blockIdx.y * 128, n0 = blockIdx.x * 128;

  f32x4 acc[4][4];
#pragma unroll
  for (int m = 0; m < 4; ++m)
#pragma unroll
    for (int n = 0; n < 4; ++n) acc[m][n] = (f32x4){0.f, 0.f, 0.f, 0.f};

  gemm_mainloop(xbf + (size_t)m0 * 1024, W + (size_t)n0 * 1024, ldsA, ldsB, acc, tid);

  const int lane = tid & 63;
  const int wr = (tid >> 7) & 1, wc = (tid >> 6) & 1;
  const int hi = lane >> 4, lo = lane & 15;
  if (z < 2) {
    unsigned short* dst = (z == 0) ? Qb : Kb;
#pragma unroll
    for (int m = 0; m < 4; ++m)
#pragma unroll
      for (int n = 0; n < 4; ++n)
#pragma unroll
        for (int r = 0; r < 4; ++r) {
          int row = m0 + wr * 64 + m * 16 + hi * 4 + r;
          int col = n0 + wc * 64 + n * 16 + lo;
          dst[(size_t)row * 1024 + col] = bfu(acc[m][n][r]);
        }
  } else {
    // V^T: [B,H,64,S]; lane's 4 acc values are 4 consecutive s -> 8B packed store
#pragma unroll
    for (int m = 0; m < 4; ++m)
#pragma unroll
      for (int n = 0; n < 4; ++n) {
        int col = n0 + wc * 64 + n * 16 + lo;
        int hh = col >> 6, hd = col & 63;
        int row0 = m0 + wr * 64 + m * 16 + hi * 4;
        int b_ = row0 >> 11, s_ = row0 & 2047;
        u16x4 pk;
#pragma unroll
        for (int r = 0; r < 4; ++r) pk[r] = bfu(acc[m][n][r]);
        *(u16x4*)(Vt + ((size_t)((b_ * 16 + hh) * 64 + hd)) * 2048 + s_) = pk;
      }
  }
}

// ---------------------------------------------------------------------------
// Output projection: out(f32) = O(bf16) * Wo^T
// ---------------------------------------------------------------------------
__global__ __launch_bounds__(256, 2) void gemm_out(
    const unsigned short* __restrict__ Ob, const unsigned short* __restrict__ wo,
    float* __restrict__ out) {
  __shared__ __align__(16) unsigned short ldsA[128 * 32];
  __shared__ __align__(16) unsigned short ldsB[128 * 32];
  const int tid = threadIdx.x;
  const int m0 = blockIdx.y * 128, n0 = blockIdx.x * 128;
  f32x4 acc[4][4];
#pragma unroll
  for (int m = 0; m < 4; ++m)
#pragma unroll
    for (int n = 0; n < 4; ++n) acc[m][n] = (f32x4){0.f, 0.f, 0.f, 0.f};
  gemm_mainloop(Ob + (size_t)m0 * 1024, wo + (size_t)n0 * 1024, ldsA, ldsB, acc, tid);
  const int lane = tid & 63;
  const int wr = (tid >> 7) & 1, wc = (tid >> 6) & 1;
  const int hi = lane >> 4, lo = lane & 15;
#pragma unroll
  for (int m = 0; m < 4; ++m)
#pragma unroll
    for (int n = 0; n < 4; ++n)
#pragma unroll
      for (int r = 0; r < 4; ++r) {
        int row = m0 + wr * 64 + m * 16 + hi * 4 + r;
        int col = n0 + wc * 64 + n * 16 + lo;
        out[(size_t)row * 1024 + col] = acc[m][n][r];
      }
}

// ---------------------------------------------------------------------------
// Flash attention, R12: R11's τ-permuted in-lane P construction, with
// __launch_bounds__(256,3).  (256,4) forced a 64-VGPR split (R2/R11 both) ->
// spills (FETCH 243MB/WRITE 240MB).  (256,3)'s 170-reg budget holds the
// ~84-VGPR body with zero spill at 3 blocks/CU (vs R9's 2).
//   τ: kf A-row lo of block n holds kv = (n&1)*32+(lo>>2)*8+(lo&3)*2+(n>>1)
//   => after QK^T lane holds kv = (n&1)*32 + hi*8 + r*2 + (n>>1), which is
//   exactly the PV B-claim set {kk*32+hi*8+j}: pb[kk][j]=sc[2*(j&1)+kk][j>>1].
//   Softmax is kv-symmetric so the relabeling is benign.
// ---------------------------------------------------------------------------
__global__ __launch_bounds__(256, 3) void attn_kernel(
    const unsigned short* __restrict__ Qb, const unsigned short* __restrict__ Kb,
    const unsigned short* __restrict__ Vt, unsigned short* __restrict__ Ob) {
  __shared__ __align__(16) unsigned short K0[64 * 64];
  __shared__ __align__(16) unsigned short K1[64 * 64];
  __shared__ __align__(16) unsigned short V0[64 * 64];
  __shared__ __align__(16) unsigned short V1[64 * 64];

  const int tid = threadIdx.x, lane = tid & 63, wave = tid >> 6;
  const int hi = lane >> 4, lo = lane & 15;

  // XCD-aware bijective swizzle: 1024 blocks = 8 XCDs x 128 work items.
  const int lin = blockIdx.x;
  const int wid = (lin & 7) * 128 + (lin >> 3);
  const int bh = wid >> 4, qt = wid & 15;
  const int b = bh >> 4, h = bh & 15;

  const unsigned short* Qg = Qb + (size_t)(b * S + qt * 128) * D + h * 64;
  const unsigned short* Kg = Kb + (size_t)b * S * D + h * 64;
  const unsigned short* Vg = Vt + (size_t)bh * 64 * S;

  // Q fragments (B-operand): lane holds Q[q=wave*32+m*16+lo][d=kk*32+hi*8..+7]
  bfrag8 qf[2][2];
#pragma unroll
  for (int m = 0; m < 2; ++m)
#pragma unroll
    for (int kk = 0; kk < 2; ++kk)
      qf[m][kk] =
          *(const bfrag8*)(Qg + (size_t)(wave * 32 + m * 16 + lo) * D + kk * 32 + hi * 8);

  // O^T accumulators: oT[n][m] reg r -> d = n*16+hi*4+r, q = m*16+lo
  f32x4 oT[4][2];
  float mrow[2], lrow[2];
#pragma unroll
  for (int n = 0; n < 4; ++n)
#pragma unroll
    for (int m = 0; m < 2; ++m) oT[n][m] = (f32x4){0.f, 0.f, 0.f, 0.f};
  mrow[0] = mrow[1] = -__builtin_inff();
  lrow[0] = lrow[1] = 0.f;

  // stage one KV tile (16KB); XOR swizzle via pre-swizzled global source
  auto stage = [&](unsigned short* kl, unsigned short* vl, int kv0) {
#pragma unroll
    for (int i = 0; i < 2; ++i) {
      int c = tid + i * 256;                      // 512 chunks per 8KB tile
      int row = c >> 3, sl = (c & 7) ^ (row & 7); // pre-swizzled source slot
      int ldsoff = ((tid & ~63) + i * 256) * 16;
      GLOAD16(Kg + (size_t)(kv0 + row) * D + sl * 8, (char*)kl + ldsoff);
      GLOAD16(Vg + (size_t)row * S + kv0 + sl * 8, (char*)vl + ldsoff);
    }
  };

  auto compute = [&](const unsigned short* Kc, const unsigned short* Vc) {
    const float c1 = 0.125f * 1.4426950408889634f;  // scale * log2(e)
    // K fragments (A-operand), kv-permuted rows (τ): see header comment.
    bfrag8 kf[4][2];
#pragma unroll
    for (int n = 0; n < 4; ++n) {
      const int row = (n & 1) * 32 + (lo >> 2) * 8 + (lo & 3) * 2 + (n >> 1);
#pragma unroll
      for (int kk = 0; kk < 2; ++kk)
        kf[n][kk] = *(const bfrag8*)(Kc + row * 64 + (((kk * 4 + hi) ^ (row & 7)) * 8));
    }
    // S^T: sc[n][m] reg r -> kv = (n&1)*32 + hi*8 + r*2 + (n>>1), q = m*16+lo
    f32x4 sc[4][2];
#pragma unroll
    for (int n = 0; n < 4; ++n)
#pragma unroll
      for (int m = 0; m < 2; ++m) {
        sc[n][m] = (f32x4){0.f, 0.f, 0.f, 0.f};
#pragma unroll
        for (int kk = 0; kk < 2; ++kk)
          sc[n][m] = __builtin_amdgcn_mfma_f32_16x16x32_bf16(kf[n][kk], qf[m][kk],
                                                             sc[n][m], 0, 0, 0);
      }
    // V^T fragments (A-operand for O^T): row d = n*16+lo, k-chunk kv = kk*32+hi*8
    bfrag8 vf[4][2];
#pragma unroll
    for (int n = 0; n < 4; ++n)
#pragma unroll
      for (int kk = 0; kk < 2; ++kk) {
        int row = n * 16 + lo;
        vf[n][kk] = *(const bfrag8*)(Vc + row * 64 + (((kk * 4 + hi) ^ (row & 7)) * 8));
      }

#pragma unroll
    for (int m = 0; m < 2; ++m) {
      // softmax for q = m*16+lo: 16 in-lane kv values + reduce across hi
      float mx = sc[0][m][0];
#pragma unroll
      for (int n = 0; n < 4; ++n)
#pragma unroll
        for (int r = 0; r < 4; ++r)
          if (!(n == 0 && r == 0)) mx = fmaxf(mx, sc[n][m][r]);
      mx = fmaxf(mx, __shfl_xor(mx, 16));
      mx = fmaxf(mx, __shfl_xor(mx, 32));
      float Mnew = fmaxf(mrow[m], mx * c1);
      float alpha = __builtin_amdgcn_exp2f(mrow[m] - Mnew);
      float ps = 0.f;
#pragma unroll
      for (int n = 0; n < 4; ++n)
#pragma unroll
        for (int r = 0; r < 4; ++r) {
          float p = __builtin_amdgcn_exp2f(sc[n][m][r] * c1 - Mnew);
          sc[n][m][r] = p;
          ps += p;
        }
      ps += __shfl_xor(ps, 16);
      ps += __shfl_xor(ps, 32);
      lrow[m] = lrow[m] * alpha + ps;
      mrow[m] = Mnew;
#pragma unroll
      for (int n = 0; n < 4; ++n)
#pragma unroll
        for (int r = 0; r < 4; ++r) oT[n][m][r] *= alpha;

      // PV B-operand, fully in-lane: pb[kk] elem j = P[kv=kk*32+hi*8+j][q]
#pragma unroll
      for (int kk = 0; kk < 2; ++kk) {
        u16x8 pw;
#pragma unroll
        for (int j = 0; j < 8; ++j) pw[j] = bfu(sc[2 * (j & 1) + kk][m][j >> 1]);
        bfrag8 pb = __builtin_bit_cast(bfrag8, pw);
#pragma unroll
        for (int n = 0; n < 4; ++n)
          oT[n][m] = __builtin_amdgcn_mfma_f32_16x16x32_bf16(vf[n][kk], pb,
                                                             oT[n][m], 0, 0, 0);
      }
    }
  };

  stage(K0, V0, 0);
  for (int t = 0; t < 32; t += 2) {
    stage(K1, V1, (t + 1) * 64);    // prefetch odd tile (stays in flight)
    VMW4;                           // drain even tile only
    BAR();
    compute(K0, V0);
    BAR();                          // all reads of K0/V0 done
    if (t + 2 < 32) {
      stage(K0, V0, (t + 2) * 64);  // prefetch next even tile
      VMW4;                         // drain odd tile only
    } else {
      VMW0;
    }
    BAR();
    compute(K1, V1);
    BAR();                          // all reads of K1/V1 done
  }

  // epilogue: O^T[d][q] -> O rows q = wave*32+m*16+lo, d = n*16+hi*4+r
#pragma unroll
  for (int m = 0; m < 2; ++m) {
    float inv = 1.f / lrow[m];
    size_t qrow = (size_t)(b * S + qt * 128 + wave * 32 + m * 16 + lo) * D + h * 64;
#pragma unroll
    for (int n = 0; n < 4; ++n) {
      u16x4 p4;
#pragma unroll
      for (int r = 0; r < 4; ++r) p4[r] = bfu(oT[n][m][r] * inv);
      *(u16x4*)(Ob + qrow + n * 16 + hi * 4) = p4;
    }
  }
}

// ---------------------------------------------------------------------------
extern "C" void kernel_launch(void* const* d_in, const int* in_sizes, int n_in,
                              void* d_out, int out_size, void* d_ws, size_t ws_size,
                              hipStream_t stream) {
  const float* x = (const float*)d_in[0];
  const float* wq = (const float*)d_in[1];
  const float* wk = (const float*)d_in[2];
  const float* wv = (const float*)d_in[3];
  const float* wo = (const float*)d_in[4];
  float* out = (float*)d_out;

  unsigned short* base = (unsigned short*)d_ws;
  unsigned short* xbf = base;              // XN
  unsigned short* wqb = xbf + XN;          // WN
  unsigned short* wkb = wqb + WN;
  unsigned short* wvb = wkb + WN;
  unsigned short* wob = wvb + WN;
  unsigned short* Qb = wob + WN;           // XN
  unsigned short* Kb = Qb + XN;            // XN
  unsigned short* Vt = Kb + XN;            // XN  ([B,H,64,S])
  unsigned short* Ob = Vt + XN;            // XN

  convert_kernel<<<dim3(6144), dim3(256), 0, stream>>>(x, wq, wk, wv, wo, xbf);
  gemm_qkv<<<dim3(8, 64, 3), dim3(256), 0, stream>>>(xbf, wqb, wkb, wvb, Qb, Kb, Vt);
  attn_kernel<<<dim3(1024), dim3(256), 0, stream>>>(Qb, Kb, Vt, Ob);
  gemm_out<<<dim3(8, 64), dim3(256), 0, stream>>>(Ob, wob, out);
}